// Round 4
// baseline (286.835 us; speedup 1.0000x reference)
//
#include <hip/hip_runtime.h>

typedef unsigned short u16;
typedef __bf16 bf16x8 __attribute__((ext_vector_type(8)));
typedef float f32x4 __attribute__((ext_vector_type(4)));
typedef float f32x16 __attribute__((ext_vector_type(16)));

// Problem constants
#define M_DIM 8192      // BATCH*SEQ
#define K_DIM 1024      // MAX_D_IN
#define N_EFF 3072      // nonzero output columns
#define N_FULL 6144     // MAX_D_OUT
#define BM 128
#define BN 128
#define BK 32           // per sub-tile; 2 sub-tiles staged per barrier

// ---- helpers ----------------------------------------------------------------
__device__ __forceinline__ u16 f2bf_rne(float f) {
    unsigned u = __float_as_uint(f);
    u += 0x7fffu + ((u >> 16) & 1u);
    return (u16)(u >> 16);
}

__device__ __forceinline__ void gld_lds16(const u16* g, u16* l) {
    // async global->LDS, 16B per lane; LDS dest = wave-uniform base + lane*16,
    // our chunk indexing keeps lane-order == contiguous LDS order.
    __builtin_amdgcn_global_load_lds(
        (const __attribute__((address_space(1))) unsigned int*)g,
        (__attribute__((address_space(3))) unsigned int*)l, 16, 0, 0);
}

// ---- prep: x fp32 -> bf16 ---------------------------------------------------
__global__ void cvt_x(const float* __restrict__ in, u16* __restrict__ out, int n8) {
    int i = blockIdx.x * 256 + threadIdx.x;
    if (i >= n8) return;
    const float4* p = reinterpret_cast<const float4*>(in) + 2 * (size_t)i;
    float4 a = p[0], b = p[1];
    union { u16 h[8]; uint4 v; } r;
    float vals[8] = {a.x, a.y, a.z, a.w, b.x, b.y, b.z, b.w};
#pragma unroll
    for (int j = 0; j < 8; j++) r.h[j] = f2bf_rne(vals[j]);
    reinterpret_cast<uint4*>(out)[i] = r.v;
}

// ---- prep: W_mix = W * M(o,i) -> bf16 (rows [0,3072) only) ------------------
__global__ void prep_w(const float* __restrict__ W, const float* __restrict__ wt,
                       u16* __restrict__ Wm, int n8) {
    int i = blockIdx.x * 256 + threadIdx.x;
    if (i >= n8) return;
    float w01 = wt[0] + wt[1], w23 = wt[2] + wt[3], w45 = wt[4] + wt[5];
    int o = i >> 7;              // row (128 chunks of 8 per 1024-wide row)
    int ib = (i & 127) * 8;      // column base; 512/768 are multiples of 8
    float s = w45;
    if (o < 2304 && ib < 768) s += w23;
    if (o < 1536 && ib < 512) s += w01;
    const float4* p = reinterpret_cast<const float4*>(W) + 2 * (size_t)i;
    float4 a = p[0], b = p[1];
    union { u16 h[8]; uint4 v; } r;
    float vals[8] = {a.x, a.y, a.z, a.w, b.x, b.y, b.z, b.w};
#pragma unroll
    for (int j = 0; j < 8; j++) r.h[j] = f2bf_rne(vals[j] * s);
    reinterpret_cast<uint4*>(Wm)[i] = r.v;
}

// ---- GEMM: C[m,n] = sum_k A[m,k]*B[n,k] + b[n]*s(n); zero-fills n+3072 ------
// r3 structure (2x BK=32 sub-tiles per barrier, 16 barriers) but inner compute
// switched to 32x32x16 MFMA (2495 TF ubench vs ~2176 for 16x16x32; half the
// MFMA instruction count). Wave = 64x64 via 2x2 grid of 32x32 tiles.
__global__ __launch_bounds__(256, 3) void gemm_bt(
    const u16* __restrict__ A,   // [8192][1024] bf16
    const u16* __restrict__ B,   // [3072][1024] bf16 (row = output col)
    const float* __restrict__ bias, // raw b[6144] fp32
    const float* __restrict__ wt,   // weights[6]
    float* __restrict__ C)       // [8192][6144] fp32
{
    __shared__ u16 As[2 * BM * BK];  // 16 KB: sub-tile st at offset st*4096
    __shared__ u16 Bs[2 * BN * BK];  // 16 KB

    const int tid  = threadIdx.x;
    const int bx   = blockIdx.x;   // N tile 0..23
    const int by   = blockIdx.y;   // M tile 0..63
    const int lane = tid & 63;
    const int wv   = tid >> 6;
    const int wm   = (wv >> 1) * 64;  // wave row offset in tile
    const int wn   = (wv & 1) * 64;   // wave col offset in tile

    f32x16 acc[2][2] = {};            // 64 AGPRs

    const u16* Ag = A + (size_t)(by * BM) * K_DIM;
    const u16* Bg = B + (size_t)(bx * BN) * K_DIM;

    const int r32 = lane & 31;        // m (A) / n (B) within 32-tile
    const int kh  = lane >> 5;        // k-half selector: lane holds k = kh*8+j

    for (int kt = 0; kt < K_DIM; kt += 2 * BK) {
        __syncthreads();  // protect previous iteration's LDS reads
#pragma unroll
        for (int u = 0; u < 4; u++) {
            int c  = u * 256 + tid;        // chunk index 0..1023, 16B each
            int st = c >> 9;               // sub-tile 0/1
            int c2 = c & 511;
            int row = c2 >> 2, kc = (c2 & 3) * 8;
            size_t goff = (size_t)row * K_DIM + kt + st * BK + kc;
            gld_lds16(Ag + goff, &As[c * 8]);
            gld_lds16(Bg + goff, &Bs[c * 8]);
        }
        __syncthreads();  // drains vmcnt before reads

#pragma unroll
        for (int st = 0; st < 2; st++) {
            // A-frag (32x32x16): m=lane&31, k=(lane>>5)*8+j; h picks k 0-15/16-31
            bf16x8 af[2][2], bq[2][2];   // [tile][khalf]
#pragma unroll
            for (int t = 0; t < 2; t++)
#pragma unroll
                for (int h = 0; h < 2; h++) {
                    af[t][h] = *reinterpret_cast<const bf16x8*>(
                        &As[st * 4096 + (wm + t * 32 + r32) * BK + h * 16 + kh * 8]);
                    bq[t][h] = *reinterpret_cast<const bf16x8*>(
                        &Bs[st * 4096 + (wn + t * 32 + r32) * BK + h * 16 + kh * 8]);
                }
#pragma unroll
            for (int h = 0; h < 2; h++)
#pragma unroll
                for (int tm = 0; tm < 2; tm++)
#pragma unroll
                    for (int tn = 0; tn < 2; tn++)
                        acc[tm][tn] = __builtin_amdgcn_mfma_f32_32x32x16_bf16(
                            af[tm][h], bq[tn][h], acc[tm][tn], 0, 0, 0);
        }
    }

    // Fused bias: s(n) = w45 + (n<2304)*w23 + (n<1536)*w01
    const float w01 = wt[0] + wt[1], w23 = wt[2] + wt[3], w45 = wt[4] + wt[5];

    // Epilogue: 32x32 C/D layout col=lane&31 (n), row=(reg&3)+8*(reg>>2)+4*kh.
    const int m0 = by * BM + wm + kh * 4;
    const int n0 = bx * BN + wn + r32;
#pragma unroll
    for (int tn = 0; tn < 2; tn++) {
        int n = n0 + tn * 32;
        float s = w45 + (n < 2304 ? w23 : 0.f) + (n < 1536 ? w01 : 0.f);
        float bv = bias[n] * s;
#pragma unroll
        for (int tm = 0; tm < 2; tm++) {
            int mb = m0 + tm * 32;
#pragma unroll
            for (int r = 0; r < 16; r++) {
                int m = mb + (r >> 2) * 8 + (r & 3);
                __builtin_nontemporal_store(acc[tm][tn][r] + bv,
                    &C[(size_t)m * N_FULL + n]);
            }
        }
    }

    // Zero-fill the mirror tile at columns [3072+bx*128, +128): exact zeros in ref.
    const f32x4 z = {0.f, 0.f, 0.f, 0.f};
#pragma unroll
    for (int it = 0; it < 16; it++) {
        int lin = it * 256 + tid;        // 0..4095 -> 128 rows x 32 float4
        int row = lin >> 5;
        int c4  = (lin & 31) * 4;
        __builtin_nontemporal_store(z, reinterpret_cast<f32x4*>(
            &C[(size_t)(by * BM + row) * N_FULL + N_EFF + bx * BN + c4]));
    }
}

// ---- launch -----------------------------------------------------------------
extern "C" void kernel_launch(void* const* d_in, const int* in_sizes, int n_in,
                              void* d_out, int out_size, void* d_ws, size_t ws_size,
                              hipStream_t stream) {
    const float* x   = (const float*)d_in[0];  // [8,1024,1024]
    const float* wts = (const float*)d_in[1];  // [6]
    const float* W   = (const float*)d_in[2];  // [6144,1024]
    const float* b   = (const float*)d_in[3];  // [6144]
    float* out = (float*)d_out;                // [8192,6144]

    // workspace: xb 16 MB | Wm 6 MB
    u16* xb = (u16*)d_ws;
    u16* Wm = (u16*)((char*)d_ws + 16777216);

    cvt_x <<<4096, 256, 0, stream>>>(x, xb, M_DIM * K_DIM / 8);      // 1,048,576 chunks
    prep_w<<<1536, 256, 0, stream>>>(W, wts, Wm, N_EFF * K_DIM / 8); // 393,216 chunks
    gemm_bt<<<dim3(N_EFF / BN, M_DIM / BM), 256, 0, stream>>>(xb, Wm, b, wts, out);
}